// Round 1
// baseline (258.594 us; speedup 1.0000x reference)
//
#include <hip/hip_runtime.h>
#include <hip/hip_bf16.h>
#include <stdint.h>

#define NUM_IN  2048
#define NUM_OUT 8192
#define BATCH   4096
#define SD      5

#define BM 128
#define BN 128
#define BK 64

typedef __bf16 bf16x8 __attribute__((ext_vector_type(8)));
typedef float  f32x4  __attribute__((ext_vector_type(4)));
typedef unsigned short ushort_t;

static __device__ __forceinline__ ushort_t bf16_bits(float f) {
  __hip_bfloat16 h = __float2bfloat16(f);
  ushort_t u;
  __builtin_memcpy(&u, &h, 2);
  return u;
}

// ---------- inputs f32 -> bf16 (vectorized) ----------
__global__ __launch_bounds__(256) void cvt_kernel(const float* __restrict__ x,
                                                  ushort_t* __restrict__ y) {
  const int i = (blockIdx.x * 256 + threadIdx.x) * 8;
  float4 v0 = *reinterpret_cast<const float4*>(x + i);
  float4 v1 = *reinterpret_cast<const float4*>(x + i + 4);
  typedef ushort_t ushort8 __attribute__((ext_vector_type(8)));
  ushort8 o;
  o[0] = bf16_bits(v0.x); o[1] = bf16_bits(v0.y);
  o[2] = bf16_bits(v0.z); o[3] = bf16_bits(v0.w);
  o[4] = bf16_bits(v1.x); o[5] = bf16_bits(v1.y);
  o[6] = bf16_bits(v1.z); o[7] = bf16_bits(v1.w);
  *reinterpret_cast<ushort8*>(y + i) = o;
}

// ---------- W^T generation: Wt[n][k] bf16 ----------
__global__ __launch_bounds__(256) void genw_kernel(
    const float* __restrict__ in_pos, const float* __restrict__ out_pos,
    const float* __restrict__ init_in, const float* __restrict__ init_out,
    ushort_t* __restrict__ Wt) {
  const int idx = blockIdx.x * 256 + threadIdx.x;   // over NUM_OUT*NUM_IN
  const int n = idx >> 11;            // / NUM_IN
  const int k = idx & (NUM_IN - 1);
  float d1 = 0.f, d0 = 0.f;
#pragma unroll
  for (int d = 0; d < SD; ++d) {
    float a = in_pos[k * SD + d] - out_pos[n * SD + d];
    float b = init_in[k * SD + d] - init_out[n * SD + d];
    d1 += a * a;
    d0 += b * b;
  }
  Wt[idx] = bf16_bits(sqrtf(d1) - sqrtf(d0));
}

// ---------- GEMM: C[M][N] = A[M][K] * Wt[N][K]^T + bias ----------
// m97 structure: 128x128 tile, BK=64, 4 waves (2x2), 16x16x32 bf16 MFMA,
// global_load_lds width=16, 2 barriers per K-step.
__global__ __launch_bounds__(256) void gemm_kernel(
    const ushort_t* __restrict__ A,    // [BATCH][NUM_IN] bf16
    const ushort_t* __restrict__ Bt,   // [NUM_OUT][NUM_IN] bf16
    const float* __restrict__ bias,    // [NUM_OUT]
    float* __restrict__ C) {           // [BATCH][NUM_OUT] f32
  __shared__ __align__(16) ushort_t sA[BM * BK];   // [128][64]
  __shared__ __align__(16) ushort_t sB[BN * BK];   // [128][64]

  const int tid = threadIdx.x;
  const int w   = tid >> 6;
  const int l   = tid & 63;
  const int m0  = blockIdx.y * BM;
  const int n0  = blockIdx.x * BN;
  const int wm  = w >> 1, wn = w & 1;

  // staging: thread t covers row = r*32 + (t>>3), col = (t&7)*8 of the tile
  const int srow = tid >> 3;
  const int scol = (tid & 7) * 8;
  const ushort_t* gA = A  + (size_t)(m0 + srow) * NUM_IN + scol;
  const ushort_t* gB = Bt + (size_t)(n0 + srow) * NUM_IN + scol;

  const int ldsbase = w * 512;   // elements; wave-uniform

  f32x4 acc[4][4];
#pragma unroll
  for (int i = 0; i < 4; ++i)
#pragma unroll
    for (int j = 0; j < 4; ++j) acc[i][j] = f32x4{0.f, 0.f, 0.f, 0.f};

  const int lrow = l & 15;
  const int lk   = (l >> 4) * 8;

  for (int kt = 0; kt < NUM_IN; kt += BK) {
#pragma unroll
    for (int r = 0; r < 4; ++r) {
      __builtin_amdgcn_global_load_lds(
          reinterpret_cast<const __attribute__((address_space(1))) uint32_t*>(
              (uintptr_t)(gA + (size_t)r * 32 * NUM_IN + kt)),
          reinterpret_cast<__attribute__((address_space(3))) uint32_t*>(
              (uintptr_t)(&sA[ldsbase + r * 2048])),
          16, 0, 0);
    }
#pragma unroll
    for (int r = 0; r < 4; ++r) {
      __builtin_amdgcn_global_load_lds(
          reinterpret_cast<const __attribute__((address_space(1))) uint32_t*>(
              (uintptr_t)(gB + (size_t)r * 32 * NUM_IN + kt)),
          reinterpret_cast<__attribute__((address_space(3))) uint32_t*>(
              (uintptr_t)(&sB[ldsbase + r * 2048])),
          16, 0, 0);
    }
    __syncthreads();

#pragma unroll
    for (int ks = 0; ks < 2; ++ks) {
      bf16x8 af[4], bfr[4];
#pragma unroll
      for (int mi = 0; mi < 4; ++mi)
        af[mi] = *reinterpret_cast<const bf16x8*>(
            &sA[(wm * 64 + mi * 16 + lrow) * BK + ks * 32 + lk]);
#pragma unroll
      for (int ni = 0; ni < 4; ++ni)
        bfr[ni] = *reinterpret_cast<const bf16x8*>(
            &sB[(wn * 64 + ni * 16 + lrow) * BK + ks * 32 + lk]);
#pragma unroll
      for (int mi = 0; mi < 4; ++mi)
#pragma unroll
        for (int ni = 0; ni < 4; ++ni)
          acc[mi][ni] = __builtin_amdgcn_mfma_f32_16x16x32_bf16(
              af[mi], bfr[ni], acc[mi][ni], 0, 0, 0);
    }
    __syncthreads();
  }

  // epilogue: C[row][col] = acc + bias[col]
  const int crow0 = m0 + wm * 64 + (l >> 4) * 4;
  const int ccol0 = n0 + wn * 64 + (l & 15);
#pragma unroll
  for (int ni = 0; ni < 4; ++ni) {
    const float bi = bias[ccol0 + ni * 16];
#pragma unroll
    for (int mi = 0; mi < 4; ++mi) {
#pragma unroll
      for (int j = 0; j < 4; ++j) {
        C[(size_t)(crow0 + mi * 16 + j) * NUM_OUT + ccol0 + ni * 16] =
            acc[mi][ni][j] + bi;
      }
    }
  }
}

extern "C" void kernel_launch(void* const* d_in, const int* in_sizes, int n_in,
                              void* d_out, int out_size, void* d_ws, size_t ws_size,
                              hipStream_t stream) {
  const float* inputs   = (const float*)d_in[0];  // [4096,2048]
  const float* init_in  = (const float*)d_in[1];  // [2048,1,5]
  const float* init_out = (const float*)d_in[2];  // [1,8192,5]
  const float* in_pos   = (const float*)d_in[3];  // [2048,1,5]
  const float* out_pos  = (const float*)d_in[4];  // [1,8192,5]
  const float* biases   = (const float*)d_in[5];  // [8192]
  float* out = (float*)d_out;                     // [4096,8192]

  // workspace: Abf (16.8MB) | Wt (33.6MB)  => 48MB of d_ws
  ushort_t* Abf = (ushort_t*)d_ws;
  ushort_t* Wt  = (ushort_t*)((char*)d_ws + (size_t)BATCH * NUM_IN * 2);

  cvt_kernel<<<(BATCH * NUM_IN) / (256 * 8), 256, 0, stream>>>(inputs, Abf);
  genw_kernel<<<(NUM_OUT * NUM_IN) / 256, 256, 0, stream>>>(
      in_pos, out_pos, init_in, init_out, Wt);
  gemm_kernel<<<dim3(NUM_OUT / BN, BATCH / BM), 256, 0, stream>>>(
      Abf, Wt, biases, out);
}

// Round 2
// 200.123 us; speedup vs baseline: 1.2922x; 1.2922x over previous
//
#include <hip/hip_runtime.h>
#include <hip/hip_bf16.h>
#include <stdint.h>

#define NUM_IN  2048   // K
#define NUM_OUT 8192   // N
#define BATCH   4096   // M
#define SD      5

#define BM 256
#define BN 256
#define BK 64
#define NT (NUM_IN / BK)   // 32 K-tiles

typedef __bf16 bf16x8 __attribute__((ext_vector_type(8)));
typedef float  f32x4  __attribute__((ext_vector_type(4)));
typedef unsigned short ushort_t;
typedef ushort_t ushort8 __attribute__((ext_vector_type(8)));

static __device__ __forceinline__ ushort_t bf16_bits(float f) {
  __hip_bfloat16 h = __float2bfloat16(f);
  ushort_t u;
  __builtin_memcpy(&u, &h, 2);
  return u;
}

// ---------- inputs f32 -> bf16 (vectorized) ----------
__global__ __launch_bounds__(256) void cvt_kernel(const float* __restrict__ x,
                                                  ushort_t* __restrict__ y) {
  const int i = (blockIdx.x * 256 + threadIdx.x) * 8;
  float4 v0 = *reinterpret_cast<const float4*>(x + i);
  float4 v1 = *reinterpret_cast<const float4*>(x + i + 4);
  ushort8 o;
  o[0] = bf16_bits(v0.x); o[1] = bf16_bits(v0.y);
  o[2] = bf16_bits(v0.z); o[3] = bf16_bits(v0.w);
  o[4] = bf16_bits(v1.x); o[5] = bf16_bits(v1.y);
  o[6] = bf16_bits(v1.z); o[7] = bf16_bits(v1.w);
  *reinterpret_cast<ushort8*>(y + i) = o;
}

// ---------- W^T generation: Wt[n][k] bf16, 8 k per thread, vector store ----------
__global__ __launch_bounds__(256) void genw_kernel(
    const float* __restrict__ in_pos, const float* __restrict__ out_pos,
    const float* __restrict__ init_in, const float* __restrict__ init_out,
    ushort_t* __restrict__ Wt) {
  const int idx = blockIdx.x * 256 + threadIdx.x;   // over NUM_OUT * (NUM_IN/8)
  const int n  = idx >> 8;                          // NUM_IN/8 = 256 chunks per n
  const int k0 = (idx & 255) * 8;
  float op[SD], iop[SD];
#pragma unroll
  for (int d = 0; d < SD; ++d) {
    op[d]  = out_pos[n * SD + d];
    iop[d] = init_out[n * SD + d];
  }
  ushort8 o;
#pragma unroll
  for (int i = 0; i < 8; ++i) {
    const int k = k0 + i;
    float d1 = 0.f, d0 = 0.f;
#pragma unroll
    for (int d = 0; d < SD; ++d) {
      float a = in_pos[k * SD + d] - op[d];
      float b = init_in[k * SD + d] - iop[d];
      d1 += a * a;
      d0 += b * b;
    }
    o[i] = bf16_bits(sqrtf(d1) - sqrtf(d0));
  }
  *reinterpret_cast<ushort8*>(Wt + (size_t)n * NUM_IN + k0) = o;
}

// ---------- GEMM: C[M][N] = A[M][K] * Bt[N][K]^T + bias ----------
// 256x256 tile, BK=64, 8 waves (2M x 4N), phase-interleaved K-step,
// chunk-XOR LDS swizzle, double-buffered, global_load_lds width=16.
__global__ __launch_bounds__(512, 2) void gemm_kernel(
    const ushort_t* __restrict__ A,    // [M][K] bf16
    const ushort_t* __restrict__ Bt,   // [N][K] bf16
    const float* __restrict__ bias,    // [N]
    float* __restrict__ C) {           // [M][N] f32
  __shared__ __align__(16) ushort_t sA[2 * BM * BK];   // 64 KiB
  __shared__ __align__(16) ushort_t sB[2 * BN * BK];   // 64 KiB

  const int tid = threadIdx.x;
  const int w   = tid >> 6;          // 0..7
  const int l   = tid & 63;
  const int wm  = w >> 2;            // 0..1
  const int wn  = w & 3;             // 0..3
  const int lrow = l & 15;
  const int lkc  = l >> 4;           // 0..3 (k-chunk within 64-k slice half)

  // bijective XCD swizzle: 512 blocks, 64 per XCD, B-panel-major within XCD
  const int orig = blockIdx.x;
  const int lin  = (orig & 7) * 64 + (orig >> 3);
  const int bx   = lin >> 4;         // 0..31  (N blocks)
  const int by   = lin & 15;         // 0..15  (M blocks)
  const int m0   = by * BM;
  const int n0   = bx * BN;

  // staging: 4 chunk-loads per thread per operand per K-tile
  // chunk idx = tid + r*512 ; row = idx>>3, c = idx&7 ; src chunk = c ^ (row&7)
  const int ldsbase = w * 512;       // elements (w*1024 bytes), wave-uniform

  f32x4 acc[8][4];
#pragma unroll
  for (int i = 0; i < 8; ++i)
#pragma unroll
    for (int j = 0; j < 4; ++j) acc[i][j] = f32x4{0.f, 0.f, 0.f, 0.f};

#define STAGE(bufsel, kt)                                                          \
  {                                                                                \
    _Pragma("unroll")                                                              \
    for (int r = 0; r < 4; ++r) {                                                  \
      const int idx = tid + r * 512;                                               \
      const int row = idx >> 3, c = idx & 7;                                       \
      const int sc  = c ^ (row & 7);                                               \
      __builtin_amdgcn_global_load_lds(                                            \
          reinterpret_cast<const __attribute__((address_space(1))) uint32_t*>(     \
              (uintptr_t)(A + (size_t)(m0 + row) * NUM_IN + (kt) + sc * 8)),       \
          reinterpret_cast<__attribute__((address_space(3))) uint32_t*>(           \
              (uintptr_t)(&sA[(bufsel) * 16384 + ldsbase + r * 4096])),            \
          16, 0, 0);                                                               \
    }                                                                              \
    _Pragma("unroll")                                                              \
    for (int r = 0; r < 4; ++r) {                                                  \
      const int idx = tid + r * 512;                                               \
      const int row = idx >> 3, c = idx & 7;                                       \
      const int sc  = c ^ (row & 7);                                               \
      __builtin_amdgcn_global_load_lds(                                            \
          reinterpret_cast<const __attribute__((address_space(1))) uint32_t*>(     \
              (uintptr_t)(Bt + (size_t)(n0 + row) * NUM_IN + (kt) + sc * 8)),      \
          reinterpret_cast<__attribute__((address_space(3))) uint32_t*>(           \
              (uintptr_t)(&sB[(bufsel) * 16384 + ldsbase + r * 4096])),            \
          16, 0, 0);                                                               \
    }                                                                              \
  }

  // fragment read with the same chunk-XOR swizzle
#define LDA(mh, mi, kk)                                                            \
  (*reinterpret_cast<const bf16x8*>(                                               \
      &sA[curoff + (wm * 128 + (mh) * 64 + (mi) * 16 + lrow) * 64 +                \
          (((kk) * 4 + lkc) ^ (lrow & 7)) * 8]))
#define LDB(nh, ni, kk)                                                            \
  (*reinterpret_cast<const bf16x8*>(                                               \
      &sB[curoff + (wn * 64 + (nh) * 32 + (ni) * 16 + lrow) * 64 +                 \
          (((kk) * 4 + lkc) ^ (lrow & 7)) * 8]))

  // prologue: stage tile 0 into buf 0
  STAGE(0, 0)
  asm volatile("s_waitcnt vmcnt(0)" ::: "memory");
  __builtin_amdgcn_s_barrier();
  __builtin_amdgcn_sched_barrier(0);

  for (int t = 0; t < NT; ++t) {
    const int curoff = (t & 1) * 16384;
    bf16x8 a[4][2], b0[2][2], b1[2][2];

    // ---- phase 0: A(mh=0) + B(nh=0) reads, prefetch next tile, 16 MFMA ----
#pragma unroll
    for (int mi = 0; mi < 4; ++mi) {
      a[mi][0] = LDA(0, mi, 0);
      a[mi][1] = LDA(0, mi, 1);
    }
#pragma unroll
    for (int ni = 0; ni < 2; ++ni) {
      b0[ni][0] = LDB(0, ni, 0);
      b0[ni][1] = LDB(0, ni, 1);
    }
    if (t < NT - 1) STAGE((t & 1) ^ 1, (t + 1) * BK)
    __builtin_amdgcn_s_barrier();
    asm volatile("s_waitcnt lgkmcnt(0)" ::: "memory");
    __builtin_amdgcn_sched_barrier(0);
    __builtin_amdgcn_s_setprio(1);
#pragma unroll
    for (int mi = 0; mi < 4; ++mi)
#pragma unroll
      for (int ni = 0; ni < 2; ++ni)
#pragma unroll
        for (int kk = 0; kk < 2; ++kk)
          acc[mi][ni] = __builtin_amdgcn_mfma_f32_16x16x32_bf16(
              a[mi][kk], b0[ni][kk], acc[mi][ni], 0, 0, 0);
    __builtin_amdgcn_s_setprio(0);
    __builtin_amdgcn_s_barrier();
    __builtin_amdgcn_sched_barrier(0);

    // ---- phase 1: B(nh=1) reads, 16 MFMA ----
#pragma unroll
    for (int ni = 0; ni < 2; ++ni) {
      b1[ni][0] = LDB(1, ni, 0);
      b1[ni][1] = LDB(1, ni, 1);
    }
    __builtin_amdgcn_s_barrier();
    asm volatile("s_waitcnt lgkmcnt(0)" ::: "memory");
    __builtin_amdgcn_sched_barrier(0);
    __builtin_amdgcn_s_setprio(1);
#pragma unroll
    for (int mi = 0; mi < 4; ++mi)
#pragma unroll
      for (int ni = 0; ni < 2; ++ni)
#pragma unroll
        for (int kk = 0; kk < 2; ++kk)
          acc[mi][2 + ni] = __builtin_amdgcn_mfma_f32_16x16x32_bf16(
              a[mi][kk], b1[ni][kk], acc[mi][2 + ni], 0, 0, 0);
    __builtin_amdgcn_s_setprio(0);
    __builtin_amdgcn_s_barrier();
    __builtin_amdgcn_sched_barrier(0);

    // ---- phase 2: A(mh=1) reads, 32 MFMA (b0 and b1 still live) ----
#pragma unroll
    for (int mi = 0; mi < 4; ++mi) {
      a[mi][0] = LDA(1, mi, 0);
      a[mi][1] = LDA(1, mi, 1);
    }
    __builtin_amdgcn_s_barrier();
    asm volatile("s_waitcnt lgkmcnt(0)" ::: "memory");
    __builtin_amdgcn_sched_barrier(0);
    __builtin_amdgcn_s_setprio(1);
#pragma unroll
    for (int mi = 0; mi < 4; ++mi)
#pragma unroll
      for (int ni = 0; ni < 2; ++ni)
#pragma unroll
        for (int kk = 0; kk < 2; ++kk) {
          acc[4 + mi][ni] = __builtin_amdgcn_mfma_f32_16x16x32_bf16(
              a[mi][kk], b0[ni][kk], acc[4 + mi][ni], 0, 0, 0);
          acc[4 + mi][2 + ni] = __builtin_amdgcn_mfma_f32_16x16x32_bf16(
              a[mi][kk], b1[ni][kk], acc[4 + mi][2 + ni], 0, 0, 0);
        }
    __builtin_amdgcn_s_setprio(0);

    // ---- K-tile boundary: my prefetch landed, everyone's prefetch landed ----
    asm volatile("s_waitcnt vmcnt(0)" ::: "memory");
    __builtin_amdgcn_s_barrier();
    __builtin_amdgcn_sched_barrier(0);
  }

  // epilogue: C += bias
  const int crow0 = m0 + wm * 128 + (l >> 4) * 4;
  const int ccol0 = n0 + wn * 64 + (l & 15);
#pragma unroll
  for (int ni = 0; ni < 4; ++ni) {
    const float bi = bias[ccol0 + ni * 16];
#pragma unroll
    for (int mi = 0; mi < 8; ++mi) {
#pragma unroll
      for (int j = 0; j < 4; ++j) {
        C[(size_t)(crow0 + mi * 16 + j) * NUM_OUT + ccol0 + ni * 16] =
            acc[mi][ni][j] + bi;
      }
    }
  }
#undef STAGE
#undef LDA
#undef LDB
}

extern "C" void kernel_launch(void* const* d_in, const int* in_sizes, int n_in,
                              void* d_out, int out_size, void* d_ws, size_t ws_size,
                              hipStream_t stream) {
  const float* inputs   = (const float*)d_in[0];  // [4096,2048]
  const float* init_in  = (const float*)d_in[1];  // [2048,1,5]
  const float* init_out = (const float*)d_in[2];  // [1,8192,5]
  const float* in_pos   = (const float*)d_in[3];  // [2048,1,5]
  const float* out_pos  = (const float*)d_in[4];  // [1,8192,5]
  const float* biases   = (const float*)d_in[5];  // [8192]
  float* out = (float*)d_out;                     // [4096,8192]

  ushort_t* Abf = (ushort_t*)d_ws;
  ushort_t* Wt  = (ushort_t*)((char*)d_ws + (size_t)BATCH * NUM_IN * 2);

  cvt_kernel<<<(BATCH * NUM_IN) / (256 * 8), 256, 0, stream>>>(inputs, Abf);
  genw_kernel<<<(NUM_OUT * (NUM_IN / 8)) / 256, 256, 0, stream>>>(
      in_pos, out_pos, init_in, init_out, Wt);
  gemm_kernel<<<(BATCH / BM) * (NUM_OUT / BN), 512, 0, stream>>>(
      Abf, Wt, biases, out);
}